// Round 2
// baseline (268.501 us; speedup 1.0000x reference)
//
#include <hip/hip_runtime.h>
#include <hip/hip_bf16.h>

#define B_NUM 2
#define T_LEN 2048
#define D_DIM 1024
#define H_NUM 16
#define HD_DIM 64

using bf16x8 = __attribute__((ext_vector_type(8))) short;
using f32x4  = __attribute__((ext_vector_type(4))) float;
using u16x4  = __attribute__((ext_vector_type(4))) unsigned short;

__device__ __forceinline__ unsigned short f2bf(float f) {
    union { __hip_bfloat16 b; unsigned short u; } v;
    v.b = __float2bfloat16(f);
    return v.u;
}

__device__ __forceinline__ void gload16(const unsigned short* g, unsigned short* l) {
    __builtin_amdgcn_global_load_lds(
        (const __attribute__((address_space(1))) void*)g,
        (__attribute__((address_space(3))) void*)l, 16, 0, 0);
}

// ---------------- convert fp32 -> bf16 (x + 4 weights) ----------------
__global__ __launch_bounds__(256) void cvt5(
    const float* __restrict__ s0, const float* __restrict__ s1, const float* __restrict__ s2,
    const float* __restrict__ s3, const float* __restrict__ s4,
    unsigned short* __restrict__ d0, unsigned short* __restrict__ d1, unsigned short* __restrict__ d2,
    unsigned short* __restrict__ d3, unsigned short* __restrict__ d4,
    int c0, int c1, int c2, int c3, int c4)
{
    const float* src; unsigned short* dst; int cnt;
    switch (blockIdx.z) {
        case 0: src = s0; dst = d0; cnt = c0; break;
        case 1: src = s1; dst = d1; cnt = c1; break;
        case 2: src = s2; dst = d2; cnt = c2; break;
        case 3: src = s3; dst = d3; cnt = c3; break;
        default: src = s4; dst = d4; cnt = c4; break;
    }
    int i = (blockIdx.x * 256 + threadIdx.x) * 4;
    if (i >= cnt) return;
    float4 v = *(const float4*)(src + i);
    u16x4 o = { f2bf(v.x), f2bf(v.y), f2bf(v.z), f2bf(v.w) };
    *(u16x4*)(dst + i) = o;
}

// ---------------- m97-style 128x128 tile core ----------------
// C[m][n] = sum_k A[m][k] * Bm[n][k]  (both row-major, K contiguous)
// block = 256 threads (4 waves), wave (wr,wc) owns 64x64 of the 128x128 tile.
__device__ __forceinline__ void tile128(
    const unsigned short* __restrict__ A, const unsigned short* __restrict__ Bm,
    int m0, int n0, int K, f32x4 acc[4][4])
{
    __shared__ __align__(16) unsigned short lA[128 * 32];
    __shared__ __align__(16) unsigned short lB[128 * 32];
    const int tid  = threadIdx.x;
    const int lane = tid & 63, w = tid >> 6;
    const int g = lane >> 4, c = lane & 15;
    const int wr = w >> 1, wc = w & 1;
    const int srow = lane >> 2;        // row within 16-row staging chunk
    const int selt = (lane & 3) * 8;   // bf16 elements into the row (16B chunks)

    #pragma unroll
    for (int mi = 0; mi < 4; ++mi)
        #pragma unroll
        for (int ni = 0; ni < 4; ++ni)
            acc[mi][ni] = (f32x4){0.f, 0.f, 0.f, 0.f};

    const unsigned short* gA = A + (size_t)m0 * K + selt;
    const unsigned short* gB = Bm + (size_t)n0 * K + selt;

    for (int k0 = 0; k0 < K; k0 += 32) {
        __syncthreads();
        #pragma unroll
        for (int i = 0; i < 2; ++i) {
            const int chunk = w * 2 + i;               // 0..7 (16 rows each)
            const int row = chunk * 16 + srow;
            gload16(gA + (size_t)row * K + k0, lA + chunk * 512);
            gload16(gB + (size_t)row * K + k0, lB + chunk * 512);
        }
        asm volatile("s_waitcnt vmcnt(0)" ::: "memory");
        __syncthreads();
        bf16x8 af[4], bfr[4];
        #pragma unroll
        for (int mi = 0; mi < 4; ++mi)
            af[mi] = *(const bf16x8*)(lA + (wr * 64 + mi * 16 + c) * 32 + g * 8);
        #pragma unroll
        for (int ni = 0; ni < 4; ++ni)
            bfr[ni] = *(const bf16x8*)(lB + (wc * 64 + ni * 16 + c) * 32 + g * 8);
        #pragma unroll
        for (int mi = 0; mi < 4; ++mi)
            #pragma unroll
            for (int ni = 0; ni < 4; ++ni)
                acc[mi][ni] = __builtin_amdgcn_mfma_f32_16x16x32_bf16(af[mi], bfr[ni], acc[mi][ni], 0, 0, 0);
    }
}

// Q/K projection -> bf16 [B,H,T,HD]; grid.z selects q/k
__global__ __launch_bounds__(256) void gemm_qk(
    const unsigned short* __restrict__ A,
    const unsigned short* __restrict__ Wq, const unsigned short* __restrict__ Wk,
    const float* __restrict__ bq, const float* __restrict__ bk,
    unsigned short* __restrict__ Oq, unsigned short* __restrict__ Ok)
{
    const unsigned short* W = blockIdx.z ? Wk : Wq;
    const float* bias       = blockIdx.z ? bk : bq;
    unsigned short* Ob      = blockIdx.z ? Ok : Oq;
    const int lane = threadIdx.x & 63, w = threadIdx.x >> 6;
    const int g = lane >> 4, c = lane & 15;
    const int m0 = blockIdx.x * 128, n0 = blockIdx.y * 128;
    f32x4 acc[4][4];
    tile128(A, W, m0, n0, D_DIM, acc);
    const int wr = w >> 1, wc = w & 1;
    #pragma unroll
    for (int mi = 0; mi < 4; ++mi) {
        #pragma unroll
        for (int ni = 0; ni < 4; ++ni) {
            const int col = n0 + wc * 64 + ni * 16 + c;
            const int h = col >> 6, hd = col & 63;
            const float bb = bias[col];
            #pragma unroll
            for (int r = 0; r < 4; ++r) {
                const int row = m0 + wr * 64 + mi * 16 + g * 4 + r;
                const int b_ = row >> 11, t = row & (T_LEN - 1);
                Ob[((size_t)((b_ * H_NUM + h) * T_LEN + t)) * HD_DIM + hd] = f2bf(acc[mi][ni][r] + bb);
            }
        }
    }
}

// V^T projection: C'[f][j] = sum_k Wv[f][k] * X[j][k]  ->  VT [B,H,HD,T]
__global__ __launch_bounds__(256) void gemm_vT(
    const unsigned short* __restrict__ Wv, const unsigned short* __restrict__ X,
    const float* __restrict__ bv, unsigned short* __restrict__ VT)
{
    const int lane = threadIdx.x & 63, w = threadIdx.x >> 6;
    const int g = lane >> 4, c = lane & 15;
    const int m0 = blockIdx.x * 128, n0 = blockIdx.y * 128;
    f32x4 acc[4][4];
    tile128(Wv, X, m0, n0, D_DIM, acc);
    const int wr = w >> 1, wc = w & 1;
    #pragma unroll
    for (int mi = 0; mi < 4; ++mi) {
        #pragma unroll
        for (int ni = 0; ni < 4; ++ni) {
            const int j = n0 + wc * 64 + ni * 16 + c;   // b*T + t
            const int b_ = j >> 11, t = j & (T_LEN - 1);
            #pragma unroll
            for (int r = 0; r < 4; ++r) {
                const int f = m0 + wr * 64 + mi * 16 + g * 4 + r;   // h*64+hd
                VT[(size_t)(b_ * D_DIM + f) * T_LEN + t] = f2bf(acc[mi][ni][r] + bv[f]);
            }
        }
    }
}

// Output projection: fp32 result to d_out
__global__ __launch_bounds__(256) void gemm_out(
    const unsigned short* __restrict__ A, const unsigned short* __restrict__ W,
    const float* __restrict__ bias, float* __restrict__ Out)
{
    const int lane = threadIdx.x & 63, w = threadIdx.x >> 6;
    const int g = lane >> 4, c = lane & 15;
    const int m0 = blockIdx.x * 128, n0 = blockIdx.y * 128;
    f32x4 acc[4][4];
    tile128(A, W, m0, n0, D_DIM, acc);
    const int wr = w >> 1, wc = w & 1;
    #pragma unroll
    for (int mi = 0; mi < 4; ++mi) {
        #pragma unroll
        for (int ni = 0; ni < 4; ++ni) {
            const int col = n0 + wc * 64 + ni * 16 + c;
            const float bb = bias[col];
            #pragma unroll
            for (int r = 0; r < 4; ++r) {
                const int row = m0 + wr * 64 + mi * 16 + g * 4 + r;
                Out[(size_t)row * D_DIM + col] = acc[mi][ni][r] + bb;
            }
        }
    }
}

// ---------------- flash attention v2 ----------------
// 4 waves/block, each wave 32 q rows (2 mi), KVBLK=64, V^T input (coalesced).
__global__ __launch_bounds__(256) void attn(
    const unsigned short* __restrict__ Q, const unsigned short* __restrict__ K,
    const unsigned short* __restrict__ VT, unsigned short* __restrict__ O)
{
    __shared__ __align__(16) unsigned short pl[4][32][72];  // per-wave P tile, padded
    const int tid = threadIdx.x;
    const int lane = tid & 63, w = tid >> 6;
    const int g = lane >> 4, c = lane & 15;
    const int bh = blockIdx.y;
    const int q0 = blockIdx.x * 128 + w * 32;
    const unsigned short* Qb = Q  + (size_t)bh * T_LEN * HD_DIM;
    const unsigned short* Kb = K  + (size_t)bh * T_LEN * HD_DIM;
    const unsigned short* Vb = VT + (size_t)bh * HD_DIM * T_LEN;

    bf16x8 qf[2][2];
    #pragma unroll
    for (int mi = 0; mi < 2; ++mi)
        #pragma unroll
        for (int kk = 0; kk < 2; ++kk)
            qf[mi][kk] = *(const bf16x8*)(Qb + (size_t)(q0 + mi * 16 + c) * HD_DIM + kk * 32 + g * 8);

    f32x4 acc[2][4];
    float m2[2][4], l2[2][4];
    #pragma unroll
    for (int mi = 0; mi < 2; ++mi) {
        #pragma unroll
        for (int ni = 0; ni < 4; ++ni) acc[mi][ni] = (f32x4){0.f, 0.f, 0.f, 0.f};
        #pragma unroll
        for (int r = 0; r < 4; ++r) { m2[mi][r] = -1e30f; l2[mi][r] = 0.f; }
    }

    const int kv_end = q0 + 31;
    for (int kv0 = 0; kv0 <= kv_end; kv0 += 64) {
        // S = Q K^T : 2 mi x 4 st subtiles
        f32x4 sf[2][4];
        #pragma unroll
        for (int st = 0; st < 4; ++st) {
            bf16x8 kf0 = *(const bf16x8*)(Kb + (size_t)(kv0 + st * 16 + c) * HD_DIM + g * 8);
            bf16x8 kf1 = *(const bf16x8*)(Kb + (size_t)(kv0 + st * 16 + c) * HD_DIM + 32 + g * 8);
            #pragma unroll
            for (int mi = 0; mi < 2; ++mi) {
                f32x4 s = (f32x4){0.f, 0.f, 0.f, 0.f};
                s = __builtin_amdgcn_mfma_f32_16x16x32_bf16(qf[mi][0], kf0, s, 0, 0, 0);
                s = __builtin_amdgcn_mfma_f32_16x16x32_bf16(qf[mi][1], kf1, s, 0, 0, 0);
                sf[mi][st] = s;
            }
        }
        // scale + causal mask (C layout: row = mi*16 + g*4 + r, col = st*16 + c)
        #pragma unroll
        for (int st = 0; st < 4; ++st) {
            const int sg = kv0 + st * 16 + c;
            #pragma unroll
            for (int mi = 0; mi < 2; ++mi)
                #pragma unroll
                for (int r = 0; r < 4; ++r) {
                    const int qg = q0 + mi * 16 + g * 4 + r;
                    sf[mi][st][r] = (sg <= qg) ? sf[mi][st][r] * 0.125f : -1e30f;
                }
        }
        // online softmax per (mi, r); 16-lane group holds the row's 64 cols (4 per lane)
        #pragma unroll
        for (int mi = 0; mi < 2; ++mi)
            #pragma unroll
            for (int r = 0; r < 4; ++r) {
                float mx = fmaxf(fmaxf(sf[mi][0][r], sf[mi][1][r]),
                                 fmaxf(sf[mi][2][r], sf[mi][3][r]));
                mx = fmaxf(mx, __shfl_xor(mx, 1));
                mx = fmaxf(mx, __shfl_xor(mx, 2));
                mx = fmaxf(mx, __shfl_xor(mx, 4));
                mx = fmaxf(mx, __shfl_xor(mx, 8));
                const float mnew = fmaxf(m2[mi][r], mx);
                const float alpha = __expf(m2[mi][r] - mnew);
                float sum = 0.f;
                #pragma unroll
                for (int st = 0; st < 4; ++st) {
                    const float p = __expf(sf[mi][st][r] - mnew);
                    sf[mi][st][r] = p;
                    sum += p;
                }
                sum += __shfl_xor(sum, 1);
                sum += __shfl_xor(sum, 2);
                sum += __shfl_xor(sum, 4);
                sum += __shfl_xor(sum, 8);
                l2[mi][r] = l2[mi][r] * alpha + sum;
                m2[mi][r] = mnew;
                #pragma unroll
                for (int ni = 0; ni < 4; ++ni) acc[mi][ni][r] *= alpha;
            }
        // P: C-layout -> A-layout via per-wave LDS (wave-private, no barrier needed)
        #pragma unroll
        for (int mi = 0; mi < 2; ++mi)
            #pragma unroll
            for (int st = 0; st < 4; ++st)
                #pragma unroll
                for (int r = 0; r < 4; ++r)
                    pl[w][mi * 16 + g * 4 + r][st * 16 + c] = f2bf(sf[mi][st][r]);
        asm volatile("" ::: "memory");
        bf16x8 pa[2][2];
        #pragma unroll
        for (int mi = 0; mi < 2; ++mi)
            #pragma unroll
            for (int kk = 0; kk < 2; ++kk)
                pa[mi][kk] = *(const bf16x8*)(&pl[w][mi * 16 + c][kk * 32 + g * 8]);
        // PV: acc(32x64) += P(32x64) V(64x64), V^T rows are contiguous
        #pragma unroll
        for (int ni = 0; ni < 4; ++ni) {
            bf16x8 vf0 = *(const bf16x8*)(Vb + (size_t)(ni * 16 + c) * T_LEN + kv0 + g * 8);
            bf16x8 vf1 = *(const bf16x8*)(Vb + (size_t)(ni * 16 + c) * T_LEN + kv0 + 32 + g * 8);
            #pragma unroll
            for (int mi = 0; mi < 2; ++mi) {
                acc[mi][ni] = __builtin_amdgcn_mfma_f32_16x16x32_bf16(pa[mi][0], vf0, acc[mi][ni], 0, 0, 0);
                acc[mi][ni] = __builtin_amdgcn_mfma_f32_16x16x32_bf16(pa[mi][1], vf1, acc[mi][ni], 0, 0, 0);
            }
        }
    }
    // epilogue
    const int b_ = bh >> 4, h = bh & 15;
    #pragma unroll
    for (int mi = 0; mi < 2; ++mi)
        #pragma unroll
        for (int ni = 0; ni < 4; ++ni)
            #pragma unroll
            for (int r = 0; r < 4; ++r) {
                const int q = q0 + mi * 16 + g * 4 + r;
                O[(size_t)(b_ * T_LEN + q) * D_DIM + h * HD_DIM + ni * 16 + c] =
                    f2bf(acc[mi][ni][r] / l2[mi][r]);
            }
}

extern "C" void kernel_launch(void* const* d_in, const int* in_sizes, int n_in,
                              void* d_out, int out_size, void* d_ws, size_t ws_size,
                              hipStream_t stream)
{
    const float* x  = (const float*)d_in[0];
    const float* Wq = (const float*)d_in[1];
    const float* bq = (const float*)d_in[2];
    const float* Wk = (const float*)d_in[3];
    const float* bk = (const float*)d_in[4];
    const float* Wv = (const float*)d_in[5];
    const float* bv = (const float*)d_in[6];
    const float* Wo = (const float*)d_in[7];
    const float* bo = (const float*)d_in[8];
    float* out = (float*)d_out;

    char* ws = (char*)d_ws;
    const size_t MB = 1u << 20;
    unsigned short* xb  = (unsigned short*)(ws + 0 * MB);   // 8 MB [4096,1024]
    unsigned short* wqb = (unsigned short*)(ws + 8 * MB);   // 2 MB
    unsigned short* wkb = (unsigned short*)(ws + 10 * MB);  // 2 MB
    unsigned short* wvb = (unsigned short*)(ws + 12 * MB);  // 2 MB
    unsigned short* wob = (unsigned short*)(ws + 14 * MB);  // 2 MB
    unsigned short* qw  = (unsigned short*)(ws + 16 * MB);  // 8 MB [B,H,T,64]
    unsigned short* kw  = (unsigned short*)(ws + 24 * MB);  // 8 MB [B,H,T,64]
    unsigned short* vtw = (unsigned short*)(ws + 32 * MB);  // 8 MB [B,H,64,T]
    unsigned short* ow  = (unsigned short*)(ws + 40 * MB);  // 8 MB [B*T,1024]

    cvt5<<<dim3(4096, 1, 5), dim3(256), 0, stream>>>(
        x, Wq, Wk, Wv, Wo, xb, wqb, wkb, wvb, wob,
        B_NUM * T_LEN * D_DIM, D_DIM * D_DIM, D_DIM * D_DIM, D_DIM * D_DIM, D_DIM * D_DIM);

    gemm_qk<<<dim3((B_NUM * T_LEN) / 128, D_DIM / 128, 2), dim3(256), 0, stream>>>(
        xb, wqb, wkb, bq, bk, qw, kw);

    gemm_vT<<<dim3(D_DIM / 128, (B_NUM * T_LEN) / 128), dim3(256), 0, stream>>>(
        wvb, xb, bv, vtw);

    attn<<<dim3(T_LEN / 128, B_NUM * H_NUM), dim3(256), 0, stream>>>(qw, kw, vtw, ow);

    gemm_out<<<dim3((B_NUM * T_LEN) / 128, D_DIM / 128), dim3(256), 0, stream>>>(
        ow, wob, bo, out);
}

// Round 3
// 206.637 us; speedup vs baseline: 1.2994x; 1.2994x over previous
//
#include <hip/hip_runtime.h>
#include <hip/hip_bf16.h>

#define B_NUM 2
#define T_LEN 2048
#define D_DIM 1024
#define H_NUM 16
#define HD_DIM 64

using bf16x8 = __attribute__((ext_vector_type(8))) short;
using f32x4  = __attribute__((ext_vector_type(4))) float;
using u16x4  = __attribute__((ext_vector_type(4))) unsigned short;

__device__ __forceinline__ unsigned short f2bf(float f) {
    union { __hip_bfloat16 b; unsigned short u; } v;
    v.b = __float2bfloat16(f);
    return v.u;
}

__device__ __forceinline__ void gload16(const unsigned short* g, unsigned short* l) {
    __builtin_amdgcn_global_load_lds(
        (const __attribute__((address_space(1))) void*)g,
        (__attribute__((address_space(3))) void*)l, 16, 0, 0);
}

// ---------------- convert fp32 -> bf16 (x + 4 weights), grid-stride ----------------
__global__ __launch_bounds__(256) void cvt5(
    const float* __restrict__ s0, const float* __restrict__ s1, const float* __restrict__ s2,
    const float* __restrict__ s3, const float* __restrict__ s4,
    unsigned short* __restrict__ d0, unsigned short* __restrict__ d1, unsigned short* __restrict__ d2,
    unsigned short* __restrict__ d3, unsigned short* __restrict__ d4,
    int c0, int c1, int c2, int c3, int c4)
{
    const float* src; unsigned short* dst; int cnt;
    switch (blockIdx.z) {
        case 0: src = s0; dst = d0; cnt = c0; break;
        case 1: src = s1; dst = d1; cnt = c1; break;
        case 2: src = s2; dst = d2; cnt = c2; break;
        case 3: src = s3; dst = d3; cnt = c3; break;
        default: src = s4; dst = d4; cnt = c4; break;
    }
    const int stride = gridDim.x * 256 * 4;
    for (int i = (blockIdx.x * 256 + threadIdx.x) * 4; i < cnt; i += stride) {
        float4 v = *(const float4*)(src + i);
        u16x4 o = { f2bf(v.x), f2bf(v.y), f2bf(v.z), f2bf(v.w) };
        *(u16x4*)(dst + i) = o;
    }
}

// ---------------- 128x128 tile core, double-buffered (2-phase) ----------------
// C[m][n] = sum_k A[m][k] * Bm[n][k]  (both row-major, K contiguous)
// lds layout: [buf][A|B][128*32] shorts; caller declares 32 KB.
__device__ __forceinline__ void tile128(
    const unsigned short* __restrict__ A, const unsigned short* __restrict__ Bm,
    int m0, int n0, int K, unsigned short* lds, f32x4 acc[4][4])
{
    const int tid  = threadIdx.x;
    const int lane = tid & 63, w = tid >> 6;
    const int g = lane >> 4, c = lane & 15;
    const int wr = w >> 1, wc = w & 1;
    const int srow = lane >> 2;        // row within 16-row staging chunk
    const int selt = (lane & 3) * 8;   // bf16 elements into the row (16B chunks)
    const int chunk = w * 2;           // this wave stages chunks {chunk, chunk+1}
    const int row0 = chunk * 16 + srow;

    #pragma unroll
    for (int mi = 0; mi < 4; ++mi)
        #pragma unroll
        for (int ni = 0; ni < 4; ++ni)
            acc[mi][ni] = (f32x4){0.f, 0.f, 0.f, 0.f};

    const unsigned short* gA = A  + (size_t)m0 * K + selt;
    const unsigned short* gB = Bm + (size_t)n0 * K + selt;

    // stage(buf, k0): 128x32 A and B tiles
    auto stage = [&](int buf, int k0) {
        unsigned short* bA = lds + buf * 8192;
        unsigned short* bB = bA + 4096;
        gload16(gA + (size_t)row0 * K + k0,        bA + chunk * 512);
        gload16(gA + (size_t)(row0 + 16) * K + k0, bA + (chunk + 1) * 512);
        gload16(gB + (size_t)row0 * K + k0,        bB + chunk * 512);
        gload16(gB + (size_t)(row0 + 16) * K + k0, bB + (chunk + 1) * 512);
    };

    stage(0, 0);
    __syncthreads();               // drains vmcnt(0)
    int cur = 0;
    #pragma unroll 1
    for (int k0 = 0; k0 < K; k0 += 32) {
        const bool more = (k0 + 32) < K;
        if (more) stage(cur ^ 1, k0 + 32);   // prefetch next tile (overlaps below)
        const unsigned short* bA = lds + cur * 8192;
        const unsigned short* bB = bA + 4096;
        bf16x8 af[4], bfr[4];
        #pragma unroll
        for (int mi = 0; mi < 4; ++mi)
            af[mi] = *(const bf16x8*)(bA + (wr * 64 + mi * 16 + c) * 32 + g * 8);
        #pragma unroll
        for (int ni = 0; ni < 4; ++ni)
            bfr[ni] = *(const bf16x8*)(bB + (wc * 64 + ni * 16 + c) * 32 + g * 8);
        #pragma unroll
        for (int mi = 0; mi < 4; ++mi)
            #pragma unroll
            for (int ni = 0; ni < 4; ++ni)
                acc[mi][ni] = __builtin_amdgcn_mfma_f32_16x16x32_bf16(af[mi], bfr[ni], acc[mi][ni], 0, 0, 0);
        if (more) {
            __syncthreads();       // drains vmcnt(0)+lgkmcnt(0), flip buffers
            cur ^= 1;
        }
    }
}

// Fused QKV projection. z=0: Q, z=1: K (both [B,H,T,HD]); z=2: V^T [B,H,HD,T].
__global__ __launch_bounds__(256) void gemm_qkv(
    const unsigned short* __restrict__ X,
    const unsigned short* __restrict__ Wq, const unsigned short* __restrict__ Wk,
    const unsigned short* __restrict__ Wv,
    const float* __restrict__ bq, const float* __restrict__ bk, const float* __restrict__ bv,
    unsigned short* __restrict__ Oq, unsigned short* __restrict__ Ok, unsigned short* __restrict__ OvT)
{
    __shared__ __align__(16) unsigned short lds[2 * 2 * 4096];
    const int z = blockIdx.z;
    const int lane = threadIdx.x & 63, w = threadIdx.x >> 6;
    const int g = lane >> 4, c = lane & 15;
    const int wr = w >> 1, wc = w & 1;
    f32x4 acc[4][4];

    if (z < 2) {
        const unsigned short* W = z ? Wk : Wq;
        const float* bias       = z ? bk : bq;
        unsigned short* Ob      = z ? Ok : Oq;
        const int m0 = blockIdx.x * 128, n0 = blockIdx.y * 128;
        tile128(X, W, m0, n0, D_DIM, lds, acc);
        #pragma unroll
        for (int mi = 0; mi < 4; ++mi) {
            #pragma unroll
            for (int ni = 0; ni < 4; ++ni) {
                const int col = n0 + wc * 64 + ni * 16 + c;
                const int h = col >> 6, hd = col & 63;
                const float bb = bias[col];
                #pragma unroll
                for (int r = 0; r < 4; ++r) {
                    const int row = m0 + wr * 64 + mi * 16 + g * 4 + r;
                    const int b_ = row >> 11, t = row & (T_LEN - 1);
                    Ob[((size_t)((b_ * H_NUM + h) * T_LEN + t)) * HD_DIM + hd] = f2bf(acc[mi][ni][r] + bb);
                }
            }
        }
    } else {
        // V^T: C'[f][j] = sum_k Wv[f][k] * X[j][k]
        const int m0 = blockIdx.y * 128, n0 = blockIdx.x * 128;
        tile128(Wv, X, m0, n0, D_DIM, lds, acc);
        #pragma unroll
        for (int mi = 0; mi < 4; ++mi) {
            #pragma unroll
            for (int ni = 0; ni < 4; ++ni) {
                const int j = n0 + wc * 64 + ni * 16 + c;   // b*T + t
                const int b_ = j >> 11, t = j & (T_LEN - 1);
                #pragma unroll
                for (int r = 0; r < 4; ++r) {
                    const int f = m0 + wr * 64 + mi * 16 + g * 4 + r;   // h*64+hd
                    OvT[(size_t)(b_ * D_DIM + f) * T_LEN + t] = f2bf(acc[mi][ni][r] + bv[f]);
                }
            }
        }
    }
}

// Output projection: fp32 result to d_out
__global__ __launch_bounds__(256) void gemm_out(
    const unsigned short* __restrict__ A, const unsigned short* __restrict__ W,
    const float* __restrict__ bias, float* __restrict__ Out)
{
    __shared__ __align__(16) unsigned short lds[2 * 2 * 4096];
    const int lane = threadIdx.x & 63, w = threadIdx.x >> 6;
    const int g = lane >> 4, c = lane & 15;
    const int m0 = blockIdx.x * 128, n0 = blockIdx.y * 128;
    f32x4 acc[4][4];
    tile128(A, W, m0, n0, D_DIM, lds, acc);
    const int wr = w >> 1, wc = w & 1;
    #pragma unroll
    for (int mi = 0; mi < 4; ++mi) {
        #pragma unroll
        for (int ni = 0; ni < 4; ++ni) {
            const int col = n0 + wc * 64 + ni * 16 + c;
            const float bb = bias[col];
            #pragma unroll
            for (int r = 0; r < 4; ++r) {
                const int row = m0 + wr * 64 + mi * 16 + g * 4 + r;
                Out[(size_t)row * D_DIM + col] = acc[mi][ni][r] + bb;
            }
        }
    }
}

// ---------------- flash attention v3: intra-block kv split ----------------
// Grid (T/32, B*H). 4 waves/block share ONE 32-row q tile; wave w takes kv
// steps s = w, w+4, ... (KVBLK=64) with private online (m,l,acc); merge via LDS.
__global__ __launch_bounds__(256) void attn(
    const unsigned short* __restrict__ Q, const unsigned short* __restrict__ K,
    const unsigned short* __restrict__ VT, unsigned short* __restrict__ O)
{
    __shared__ __align__(16) float macc[4][32][64];   // 32 KB, also overlays P tiles
    __shared__ float mml[4][2][32];
    __shared__ float ltot[32];
    const int tid = threadIdx.x, lane = tid & 63, w = tid >> 6;
    const int g = lane >> 4, c = lane & 15;
    const int bh = blockIdx.y;
    const int q0 = blockIdx.x * 32;
    const unsigned short* Qb = Q  + (size_t)bh * T_LEN * HD_DIM;
    const unsigned short* Kb = K  + (size_t)bh * T_LEN * HD_DIM;
    const unsigned short* Vb = VT + (size_t)bh * HD_DIM * T_LEN;
    unsigned short* pl = (unsigned short*)&macc[0][0][0] + (size_t)w * (32 * 72);

    bf16x8 qf[2][2];
    #pragma unroll
    for (int mi = 0; mi < 2; ++mi)
        #pragma unroll
        for (int kk = 0; kk < 2; ++kk)
            qf[mi][kk] = *(const bf16x8*)(Qb + (size_t)(q0 + mi * 16 + c) * HD_DIM + kk * 32 + g * 8);

    f32x4 acc[2][4];
    float m2[2][4], l2[2][4];
    #pragma unroll
    for (int mi = 0; mi < 2; ++mi) {
        #pragma unroll
        for (int ni = 0; ni < 4; ++ni) acc[mi][ni] = (f32x4){0.f, 0.f, 0.f, 0.f};
        #pragma unroll
        for (int r = 0; r < 4; ++r) { m2[mi][r] = -1e30f; l2[mi][r] = 0.f; }
    }

    const int nsteps = (q0 + 32 + 63) >> 6;
    #pragma unroll 1
    for (int s = w; s < nsteps; s += 4) {
        const int kv0 = s << 6;
        // S = Q K^T : 2 mi x 4 st subtiles
        f32x4 sf[2][4];
        #pragma unroll
        for (int st = 0; st < 4; ++st) {
            bf16x8 kf0 = *(const bf16x8*)(Kb + (size_t)(kv0 + st * 16 + c) * HD_DIM + g * 8);
            bf16x8 kf1 = *(const bf16x8*)(Kb + (size_t)(kv0 + st * 16 + c) * HD_DIM + 32 + g * 8);
            #pragma unroll
            for (int mi = 0; mi < 2; ++mi) {
                f32x4 sacc = (f32x4){0.f, 0.f, 0.f, 0.f};
                sacc = __builtin_amdgcn_mfma_f32_16x16x32_bf16(qf[mi][0], kf0, sacc, 0, 0, 0);
                sacc = __builtin_amdgcn_mfma_f32_16x16x32_bf16(qf[mi][1], kf1, sacc, 0, 0, 0);
                sf[mi][st] = sacc;
            }
        }
        // scale + causal mask (C layout: row = mi*16 + g*4 + r, col = st*16 + c)
        #pragma unroll
        for (int st = 0; st < 4; ++st) {
            const int sg = kv0 + st * 16 + c;
            #pragma unroll
            for (int mi = 0; mi < 2; ++mi)
                #pragma unroll
                for (int r = 0; r < 4; ++r) {
                    const int qg = q0 + mi * 16 + g * 4 + r;
                    sf[mi][st][r] = (sg <= qg) ? sf[mi][st][r] * 0.125f : -1e30f;
                }
        }
        // online softmax per (mi, r); 16-lane group holds the row's 64 cols
        #pragma unroll
        for (int mi = 0; mi < 2; ++mi)
            #pragma unroll
            for (int r = 0; r < 4; ++r) {
                float mx = fmaxf(fmaxf(sf[mi][0][r], sf[mi][1][r]),
                                 fmaxf(sf[mi][2][r], sf[mi][3][r]));
                mx = fmaxf(mx, __shfl_xor(mx, 1));
                mx = fmaxf(mx, __shfl_xor(mx, 2));
                mx = fmaxf(mx, __shfl_xor(mx, 4));
                mx = fmaxf(mx, __shfl_xor(mx, 8));
                const float mnew = fmaxf(m2[mi][r], mx);
                const float alpha = __expf(m2[mi][r] - mnew);
                float sum = 0.f;
                #pragma unroll
                for (int st = 0; st < 4; ++st) {
                    const float p = __expf(sf[mi][st][r] - mnew);
                    sf[mi][st][r] = p;
                    sum += p;
                }
                sum += __shfl_xor(sum, 1);
                sum += __shfl_xor(sum, 2);
                sum += __shfl_xor(sum, 4);
                sum += __shfl_xor(sum, 8);
                l2[mi][r] = l2[mi][r] * alpha + sum;
                m2[mi][r] = mnew;
                #pragma unroll
                for (int ni = 0; ni < 4; ++ni) acc[mi][ni][r] *= alpha;
            }
        // P: C-layout -> A-layout via wave-private LDS
        #pragma unroll
        for (int mi = 0; mi < 2; ++mi)
            #pragma unroll
            for (int st = 0; st < 4; ++st)
                #pragma unroll
                for (int r = 0; r < 4; ++r)
                    pl[(mi * 16 + g * 4 + r) * 72 + st * 16 + c] = f2bf(sf[mi][st][r]);
        asm volatile("" ::: "memory");
        bf16x8 pa[2][2];
        #pragma unroll
        for (int mi = 0; mi < 2; ++mi)
            #pragma unroll
            for (int kk = 0; kk < 2; ++kk)
                pa[mi][kk] = *(const bf16x8*)(&pl[(mi * 16 + c) * 72 + kk * 32 + g * 8]);
        // PV: acc(32x64) += P(32x64) V(64x64), V^T rows contiguous
        #pragma unroll
        for (int ni = 0; ni < 4; ++ni) {
            bf16x8 vf0 = *(const bf16x8*)(Vb + (size_t)(ni * 16 + c) * T_LEN + kv0 + g * 8);
            bf16x8 vf1 = *(const bf16x8*)(Vb + (size_t)(ni * 16 + c) * T_LEN + kv0 + 32 + g * 8);
            #pragma unroll
            for (int mi = 0; mi < 2; ++mi) {
                acc[mi][ni] = __builtin_amdgcn_mfma_f32_16x16x32_bf16(pa[mi][0], vf0, acc[mi][ni], 0, 0, 0);
                acc[mi][ni] = __builtin_amdgcn_mfma_f32_16x16x32_bf16(pa[mi][1], vf1, acc[mi][ni], 0, 0, 0);
            }
        }
    }

    // ---- merge the 4 waves' partial (m, l, acc) ----
    if (c == 0) {
        #pragma unroll
        for (int mi = 0; mi < 2; ++mi)
            #pragma unroll
            for (int r = 0; r < 4; ++r) {
                const int row = mi * 16 + g * 4 + r;
                mml[w][0][row] = m2[mi][r];
                mml[w][1][row] = l2[mi][r];
            }
    }
    __syncthreads();   // all waves done with kv loop (and P-tile LDS)
    #pragma unroll
    for (int mi = 0; mi < 2; ++mi)
        #pragma unroll
        for (int r = 0; r < 4; ++r) {
            const int row = mi * 16 + g * 4 + r;
            const float ma = mml[0][0][row], mb = mml[1][0][row];
            const float mc = mml[2][0][row], md = mml[3][0][row];
            const float mt = fmaxf(fmaxf(ma, mb), fmaxf(mc, md));
            const float lt = __expf(ma - mt) * mml[0][1][row] + __expf(mb - mt) * mml[1][1][row]
                           + __expf(mc - mt) * mml[2][1][row] + __expf(md - mt) * mml[3][1][row];
            if (w == 0 && c == 0) ltot[row] = lt;
            const float f = __expf(m2[mi][r] - mt);
            #pragma unroll
            for (int ni = 0; ni < 4; ++ni) acc[mi][ni][r] *= f;
        }
    // store scaled partials (overlays the P-tile region — safe after barrier)
    #pragma unroll
    for (int mi = 0; mi < 2; ++mi)
        #pragma unroll
        for (int ni = 0; ni < 4; ++ni)
            #pragma unroll
            for (int r = 0; r < 4; ++r)
                macc[w][mi * 16 + g * 4 + r][ni * 16 + c] = acc[mi][ni][r];
    __syncthreads();
    // final: 256 threads sum 4 partials and write 8 bf16 each
    const int row = tid >> 3;
    const int c0 = (tid & 7) * 8;
    const float linv = 1.0f / ltot[row];
    const int b_ = bh >> 4, h = bh & 15;
    bf16x8 ov;
    #pragma unroll
    for (int j = 0; j < 8; ++j) {
        const float o = macc[0][row][c0 + j] + macc[1][row][c0 + j]
                      + macc[2][row][c0 + j] + macc[3][row][c0 + j];
        ov[j] = (short)f2bf(o * linv);
    }
    *(bf16x8*)(O + ((size_t)(b_ * T_LEN + q0 + row)) * D_DIM + h * HD_DIM + c0) = ov;
}

extern "C" void kernel_launch(void* const* d_in, const int* in_sizes, int n_in,
                              void* d_out, int out_size, void* d_ws, size_t ws_size,
                              hipStream_t stream)
{
    const float* x  = (const float*)d_in[0];
    const float* Wq = (const float*)d_in[1];
    const float* bq = (const float*)d_in[2];
    const float* Wk = (const float*)d_in[3];
    const float* bk = (const float*)d_in[4];
    const float* Wv = (const float*)d_in[5];
    const float* bv = (const float*)d_in[6];
    const float* Wo = (const float*)d_in[7];
    const float* bo = (const float*)d_in[8];
    float* out = (float*)d_out;

    char* ws = (char*)d_ws;
    const size_t MB = 1u << 20;
    unsigned short* xb  = (unsigned short*)(ws + 0 * MB);   // 8 MB [4096,1024]
    unsigned short* wqb = (unsigned short*)(ws + 8 * MB);   // 2 MB
    unsigned short* wkb = (unsigned short*)(ws + 10 * MB);  // 2 MB
    unsigned short* wvb = (unsigned short*)(ws + 12 * MB);  // 2 MB
    unsigned short* wob = (unsigned short*)(ws + 14 * MB);  // 2 MB
    unsigned short* qw  = (unsigned short*)(ws + 16 * MB);  // 8 MB [B,H,T,64]
    unsigned short* kw  = (unsigned short*)(ws + 24 * MB);  // 8 MB [B,H,T,64]
    unsigned short* vtw = (unsigned short*)(ws + 32 * MB);  // 8 MB [B,H,64,T]
    unsigned short* ow  = (unsigned short*)(ws + 40 * MB);  // 8 MB [B*T,1024]

    cvt5<<<dim3(1024, 1, 5), dim3(256), 0, stream>>>(
        x, Wq, Wk, Wv, Wo, xb, wqb, wkb, wvb, wob,
        B_NUM * T_LEN * D_DIM, D_DIM * D_DIM, D_DIM * D_DIM, D_DIM * D_DIM, D_DIM * D_DIM);

    gemm_qkv<<<dim3((B_NUM * T_LEN) / 128, D_DIM / 128, 3), dim3(256), 0, stream>>>(
        xb, wqb, wkb, wvb, bq, bk, bv, qw, kw, vtw);

    attn<<<dim3(T_LEN / 32, B_NUM * H_NUM), dim3(256), 0, stream>>>(qw, kw, vtw, ow);

    gemm_out<<<dim3((B_NUM * T_LEN) / 128, D_DIM / 128), dim3(256), 0, stream>>>(
        ow, wob, bo, out);
}

// Round 4
// 178.679 us; speedup vs baseline: 1.5027x; 1.1565x over previous
//
#include <hip/hip_runtime.h>
#include <hip/hip_bf16.h>

#define B_NUM 2
#define T_LEN 2048
#define D_DIM 1024
#define H_NUM 16
#define HD_DIM 64

using bf16x8 = __attribute__((ext_vector_type(8))) short;
using f32x4  = __attribute__((ext_vector_type(4))) float;
using u16x4  = __attribute__((ext_vector_type(4))) unsigned short;

__device__ __forceinline__ unsigned short f2bf(float f) {
    union { __hip_bfloat16 b; unsigned short u; } v;
    v.b = __float2bfloat16(f);
    return v.u;
}

__device__ __forceinline__ void gload16(const unsigned short* g, unsigned short* l) {
    __builtin_amdgcn_global_load_lds(
        (const __attribute__((address_space(1))) void*)g,
        (__attribute__((address_space(3))) void*)l, 16, 0, 0);
}

// ---------------- convert fp32 -> bf16 (x + 4 weights), grid-stride ----------------
__global__ __launch_bounds__(256) void cvt5(
    const float* __restrict__ s0, const float* __restrict__ s1, const float* __restrict__ s2,
    const float* __restrict__ s3, const float* __restrict__ s4,
    unsigned short* __restrict__ d0, unsigned short* __restrict__ d1, unsigned short* __restrict__ d2,
    unsigned short* __restrict__ d3, unsigned short* __restrict__ d4,
    int c0, int c1, int c2, int c3, int c4)
{
    const float* src; unsigned short* dst; int cnt;
    switch (blockIdx.z) {
        case 0: src = s0; dst = d0; cnt = c0; break;
        case 1: src = s1; dst = d1; cnt = c1; break;
        case 2: src = s2; dst = d2; cnt = c2; break;
        case 3: src = s3; dst = d3; cnt = c3; break;
        default: src = s4; dst = d4; cnt = c4; break;
    }
    const int stride = gridDim.x * 256 * 4;
    for (int i = (blockIdx.x * 256 + threadIdx.x) * 4; i < cnt; i += stride) {
        float4 v = *(const float4*)(src + i);
        u16x4 o = { f2bf(v.x), f2bf(v.y), f2bf(v.z), f2bf(v.w) };
        *(u16x4*)(dst + i) = o;
    }
}

// ---------------- 128x128 tile core, double-buffered (2-phase) ----------------
__device__ __forceinline__ void tile128(
    const unsigned short* __restrict__ A, const unsigned short* __restrict__ Bm,
    int m0, int n0, int K, unsigned short* lds, f32x4 acc[4][4])
{
    const int tid  = threadIdx.x;
    const int lane = tid & 63, w = tid >> 6;
    const int g = lane >> 4, c = lane & 15;
    const int wr = w >> 1, wc = w & 1;
    const int srow = lane >> 2;
    const int selt = (lane & 3) * 8;
    const int chunk = w * 2;
    const int row0 = chunk * 16 + srow;

    #pragma unroll
    for (int mi = 0; mi < 4; ++mi)
        #pragma unroll
        for (int ni = 0; ni < 4; ++ni)
            acc[mi][ni] = (f32x4){0.f, 0.f, 0.f, 0.f};

    const unsigned short* gA = A  + (size_t)m0 * K + selt;
    const unsigned short* gB = Bm + (size_t)n0 * K + selt;

    auto stage = [&](int buf, int k0) {
        unsigned short* bA = lds + buf * 8192;
        unsigned short* bB = bA + 4096;
        gload16(gA + (size_t)row0 * K + k0,        bA + chunk * 512);
        gload16(gA + (size_t)(row0 + 16) * K + k0, bA + (chunk + 1) * 512);
        gload16(gB + (size_t)row0 * K + k0,        bB + chunk * 512);
        gload16(gB + (size_t)(row0 + 16) * K + k0, bB + (chunk + 1) * 512);
    };

    stage(0, 0);
    __syncthreads();
    int cur = 0;
    #pragma unroll 1
    for (int k0 = 0; k0 < K; k0 += 32) {
        const bool more = (k0 + 32) < K;
        if (more) stage(cur ^ 1, k0 + 32);
        const unsigned short* bA = lds + cur * 8192;
        const unsigned short* bB = bA + 4096;
        bf16x8 af[4], bfr[4];
        #pragma unroll
        for (int mi = 0; mi < 4; ++mi)
            af[mi] = *(const bf16x8*)(bA + (wr * 64 + mi * 16 + c) * 32 + g * 8);
        #pragma unroll
        for (int ni = 0; ni < 4; ++ni)
            bfr[ni] = *(const bf16x8*)(bB + (wc * 64 + ni * 16 + c) * 32 + g * 8);
        #pragma unroll
        for (int mi = 0; mi < 4; ++mi)
            #pragma unroll
            for (int ni = 0; ni < 4; ++ni)
                acc[mi][ni] = __builtin_amdgcn_mfma_f32_16x16x32_bf16(af[mi], bfr[ni], acc[mi][ni], 0, 0, 0);
        if (more) {
            __syncthreads();
            cur ^= 1;
        }
    }
}

// Fused QKV projection. z=0: Q, z=1: K (both [B,H,T,HD]); z=2: V^T [B,H,HD,T].
__global__ __launch_bounds__(256) void gemm_qkv(
    const unsigned short* __restrict__ X,
    const unsigned short* __restrict__ Wq, const unsigned short* __restrict__ Wk,
    const unsigned short* __restrict__ Wv,
    const float* __restrict__ bq, const float* __restrict__ bk, const float* __restrict__ bv,
    unsigned short* __restrict__ Oq, unsigned short* __restrict__ Ok, unsigned short* __restrict__ OvT)
{
    __shared__ __align__(16) unsigned short lds[2 * 2 * 4096];
    const int z = blockIdx.z;
    const int lane = threadIdx.x & 63, w = threadIdx.x >> 6;
    const int g = lane >> 4, c = lane & 15;
    const int wr = w >> 1, wc = w & 1;
    f32x4 acc[4][4];

    if (z < 2) {
        const unsigned short* W = z ? Wk : Wq;
        const float* bias       = z ? bk : bq;
        unsigned short* Ob      = z ? Ok : Oq;
        const int m0 = blockIdx.x * 128, n0 = blockIdx.y * 128;
        tile128(X, W, m0, n0, D_DIM, lds, acc);
        #pragma unroll
        for (int mi = 0; mi < 4; ++mi) {
            #pragma unroll
            for (int ni = 0; ni < 4; ++ni) {
                const int col = n0 + wc * 64 + ni * 16 + c;
                const int h = col >> 6, hd = col & 63;
                const float bb = bias[col];
                #pragma unroll
                for (int r = 0; r < 4; ++r) {
                    const int row = m0 + wr * 64 + mi * 16 + g * 4 + r;
                    const int b_ = row >> 11, t = row & (T_LEN - 1);
                    Ob[((size_t)((b_ * H_NUM + h) * T_LEN + t)) * HD_DIM + hd] = f2bf(acc[mi][ni][r] + bb);
                }
            }
        }
    } else {
        const int m0 = blockIdx.y * 128, n0 = blockIdx.x * 128;
        tile128(Wv, X, m0, n0, D_DIM, lds, acc);
        #pragma unroll
        for (int mi = 0; mi < 4; ++mi) {
            #pragma unroll
            for (int ni = 0; ni < 4; ++ni) {
                const int j = n0 + wc * 64 + ni * 16 + c;
                const int b_ = j >> 11, t = j & (T_LEN - 1);
                #pragma unroll
                for (int r = 0; r < 4; ++r) {
                    const int f = m0 + wr * 64 + mi * 16 + g * 4 + r;
                    OvT[(size_t)(b_ * D_DIM + f) * T_LEN + t] = f2bf(acc[mi][ni][r] + bv[f]);
                }
            }
        }
    }
}

// Output projection: fp32 result to d_out
__global__ __launch_bounds__(256) void gemm_out(
    const unsigned short* __restrict__ A, const unsigned short* __restrict__ W,
    const float* __restrict__ bias, float* __restrict__ Out)
{
    __shared__ __align__(16) unsigned short lds[2 * 2 * 4096];
    const int lane = threadIdx.x & 63, w = threadIdx.x >> 6;
    const int g = lane >> 4, c = lane & 15;
    const int m0 = blockIdx.x * 128, n0 = blockIdx.y * 128;
    f32x4 acc[4][4];
    tile128(A, W, m0, n0, D_DIM, lds, acc);
    const int wr = w >> 1, wc = w & 1;
    #pragma unroll
    for (int mi = 0; mi < 4; ++mi) {
        #pragma unroll
        for (int ni = 0; ni < 4; ++ni) {
            const int col = n0 + wc * 64 + ni * 16 + c;
            const float bb = bias[col];
            #pragma unroll
            for (int r = 0; r < 4; ++r) {
                const int row = m0 + wr * 64 + mi * 16 + g * 4 + r;
                Out[(size_t)row * D_DIM + col] = acc[mi][ni][r] + bb;
            }
        }
    }
}

// ---------------- flash attention v4: shared LDS K/V, FA2 schedule ----------------
// 1D grid of 512 blocks; block -> (q-tile jt of 128 rows, bh), ordered so long
// tiles dispatch first and CU pairs get complementary work. 4 waves/block, each
// wave owns 32 q rows; all waves sweep the SAME kv tiles (KVBLK=64) staged in
// double-buffered LDS via global_load_lds with XOR-swizzled source (T2/rule 21).
__global__ __launch_bounds__(256) void attn(
    const unsigned short* __restrict__ Q, const unsigned short* __restrict__ K,
    const unsigned short* __restrict__ VT, unsigned short* __restrict__ O)
{
    __shared__ __align__(16) unsigned short kv_lds[2][2][64 * 64];  // [buf][K|V], 32 KB
    __shared__ __align__(16) unsigned short plbuf[4][32 * 72];      // per-wave P, 18 KB
    const int tid = threadIdx.x, lane = tid & 63, w = tid >> 6;
    const int g = lane >> 4, c = lane & 15;

    // load-balanced mapping: gid<256 -> jt 15..8 (longest first); gid>=256 -> jt 0..7
    const int gid = blockIdx.x;
    const int r5 = (gid & 255) >> 5;
    const int jt = (gid < 256) ? (15 - r5) : r5;
    const int bh = gid & 31;
    const int q0b = jt * 128;

    const unsigned short* Qb = Q  + (size_t)bh * T_LEN * HD_DIM;
    const unsigned short* Kb = K  + (size_t)bh * T_LEN * HD_DIM;
    const unsigned short* Vb = VT + (size_t)bh * HD_DIM * T_LEN;
    unsigned short* pl = plbuf[w];

    const int qw0 = q0b + w * 32;          // this wave's first q row

    // Q fragments (A-operand): lane holds row qw0+mi*16+c, k slice kk*32+g*8
    bf16x8 qf[2][2];
    #pragma unroll
    for (int mi = 0; mi < 2; ++mi)
        #pragma unroll
        for (int kk = 0; kk < 2; ++kk)
            qf[mi][kk] = *(const bf16x8*)(Qb + (size_t)(qw0 + mi * 16 + c) * HD_DIM + kk * 32 + g * 8);

    f32x4 acc[2][4];
    float m2[2][4], l2[2][4];
    #pragma unroll
    for (int mi = 0; mi < 2; ++mi) {
        #pragma unroll
        for (int ni = 0; ni < 4; ++ni) acc[mi][ni] = (f32x4){0.f, 0.f, 0.f, 0.f};
        #pragma unroll
        for (int r = 0; r < 4; ++r) { m2[mi][r] = -1e30f; l2[mi][r] = 0.f; }
    }

    // stage K(64x64) + V^T(64x64) into buf; LDS linear, global source pre-swizzled:
    // LDS[row][c16] (16B units) = G[row][c16 ^ (row&7)]
    auto stage = [&](int buf, int kv0) {
        unsigned short* kb = &kv_lds[buf][0][0];
        unsigned short* vb = &kv_lds[buf][1][0];
        #pragma unroll
        for (int rnd = 0; rnd < 2; ++rnd) {
            const int bch = rnd * 256 + w * 64;            // wave-uniform base chunk
            const int row = (bch >> 3) + (lane >> 3);
            const int sc16 = (lane & 7) ^ (row & 7);
            gload16(Kb + (size_t)(kv0 + row) * HD_DIM + sc16 * 8, kb + bch * 8);
            gload16(Vb + (size_t)row * T_LEN + kv0 + sc16 * 8,   vb + bch * 8);
        }
    };

    const int ntiles = (q0b >> 6) + 2;
    stage(0, 0);
    __syncthreads();
    int cur = 0;
    #pragma unroll 1
    for (int t = 0; t < ntiles; ++t) {
        const int kv0 = t << 6;
        if (t + 1 < ntiles) stage(cur ^ 1, kv0 + 64);
        if (kv0 <= qw0 + 31) {                 // wave has work in this tile
            const unsigned short* kb = &kv_lds[cur][0][0];
            const unsigned short* vb = &kv_lds[cur][1][0];
            // S = Q K^T : 2 mi x 4 st subtiles; swizzled ds_read_b128
            f32x4 sf[2][4];
            #pragma unroll
            for (int st = 0; st < 4; ++st) {
                const int rr = st * 16 + c;
                bf16x8 kf0 = *(const bf16x8*)(kb + rr * 64 + ((g       ^ (c & 7)) * 8));
                bf16x8 kf1 = *(const bf16x8*)(kb + rr * 64 + (((4 + g) ^ (c & 7)) * 8));
                #pragma unroll
                for (int mi = 0; mi < 2; ++mi) {
                    f32x4 s = (f32x4){0.f, 0.f, 0.f, 0.f};
                    s = __builtin_amdgcn_mfma_f32_16x16x32_bf16(qf[mi][0], kf0, s, 0, 0, 0);
                    s = __builtin_amdgcn_mfma_f32_16x16x32_bf16(qf[mi][1], kf1, s, 0, 0, 0);
                    sf[mi][st] = s;
                }
            }
            // scale + causal mask only on diagonal tiles
            if (kv0 + 63 > qw0) {
                #pragma unroll
                for (int st = 0; st < 4; ++st) {
                    const int sg = kv0 + st * 16 + c;
                    #pragma unroll
                    for (int mi = 0; mi < 2; ++mi)
                        #pragma unroll
                        for (int r = 0; r < 4; ++r) {
                            const int qg = qw0 + mi * 16 + g * 4 + r;
                            sf[mi][st][r] = (sg <= qg) ? sf[mi][st][r] * 0.125f : -1e30f;
                        }
                }
            } else {
                #pragma unroll
                for (int st = 0; st < 4; ++st)
                    #pragma unroll
                    for (int mi = 0; mi < 2; ++mi)
                        #pragma unroll
                        for (int r = 0; r < 4; ++r)
                            sf[mi][st][r] *= 0.125f;
            }
            // online softmax per (mi, r)
            #pragma unroll
            for (int mi = 0; mi < 2; ++mi)
                #pragma unroll
                for (int r = 0; r < 4; ++r) {
                    float mx = fmaxf(fmaxf(sf[mi][0][r], sf[mi][1][r]),
                                     fmaxf(sf[mi][2][r], sf[mi][3][r]));
                    mx = fmaxf(mx, __shfl_xor(mx, 1));
                    mx = fmaxf(mx, __shfl_xor(mx, 2));
                    mx = fmaxf(mx, __shfl_xor(mx, 4));
                    mx = fmaxf(mx, __shfl_xor(mx, 8));
                    const float mnew = fmaxf(m2[mi][r], mx);
                    const float alpha = __expf(m2[mi][r] - mnew);
                    float sum = 0.f;
                    #pragma unroll
                    for (int st = 0; st < 4; ++st) {
                        const float p = __expf(sf[mi][st][r] - mnew);
                        sf[mi][st][r] = p;
                        sum += p;
                    }
                    sum += __shfl_xor(sum, 1);
                    sum += __shfl_xor(sum, 2);
                    sum += __shfl_xor(sum, 4);
                    sum += __shfl_xor(sum, 8);
                    l2[mi][r] = l2[mi][r] * alpha + sum;
                    m2[mi][r] = mnew;
                    #pragma unroll
                    for (int ni = 0; ni < 4; ++ni) acc[mi][ni][r] *= alpha;
                }
            // P: C-layout -> A-layout via wave-private LDS
            #pragma unroll
            for (int mi = 0; mi < 2; ++mi)
                #pragma unroll
                for (int st = 0; st < 4; ++st)
                    #pragma unroll
                    for (int r = 0; r < 4; ++r)
                        pl[(mi * 16 + g * 4 + r) * 72 + st * 16 + c] = f2bf(sf[mi][st][r]);
            asm volatile("" ::: "memory");
            bf16x8 pa[2][2];
            #pragma unroll
            for (int mi = 0; mi < 2; ++mi)
                #pragma unroll
                for (int kk = 0; kk < 2; ++kk)
                    pa[mi][kk] = *(const bf16x8*)(&pl[(mi * 16 + c) * 72 + kk * 32 + g * 8]);
            // PV: acc(32x64) += P(32x64) V(64x64); V^T from LDS, swizzled read
            #pragma unroll
            for (int ni = 0; ni < 4; ++ni) {
                const int rr = ni * 16 + c;
                bf16x8 vf0 = *(const bf16x8*)(vb + rr * 64 + ((g       ^ (c & 7)) * 8));
                bf16x8 vf1 = *(const bf16x8*)(vb + rr * 64 + (((4 + g) ^ (c & 7)) * 8));
                #pragma unroll
                for (int mi = 0; mi < 2; ++mi) {
                    acc[mi][ni] = __builtin_amdgcn_mfma_f32_16x16x32_bf16(pa[mi][0], vf0, acc[mi][ni], 0, 0, 0);
                    acc[mi][ni] = __builtin_amdgcn_mfma_f32_16x16x32_bf16(pa[mi][1], vf1, acc[mi][ni], 0, 0, 0);
                }
            }
        }
        __syncthreads();
        cur ^= 1;
    }

    // epilogue: each wave owns its rows fully
    const int b_ = bh >> 4, h = bh & 15;
    #pragma unroll
    for (int mi = 0; mi < 2; ++mi)
        #pragma unroll
        for (int ni = 0; ni < 4; ++ni)
            #pragma unroll
            for (int r = 0; r < 4; ++r) {
                const int q = qw0 + mi * 16 + g * 4 + r;
                O[(size_t)(b_ * T_LEN + q) * D_DIM + h * HD_DIM + ni * 16 + c] =
                    f2bf(acc[mi][ni][r] / l2[mi][r]);
            }
}

extern "C" void kernel_launch(void* const* d_in, const int* in_sizes, int n_in,
                              void* d_out, int out_size, void* d_ws, size_t ws_size,
                              hipStream_t stream)
{
    const float* x  = (const float*)d_in[0];
    const float* Wq = (const float*)d_in[1];
    const float* bq = (const float*)d_in[2];
    const float* Wk = (const float*)d_in[3];
    const float* bk = (const float*)d_in[4];
    const float* Wv = (const float*)d_in[5];
    const float* bv = (const float*)d_in[6];
    const float* Wo = (const float*)d_in[7];
    const float* bo = (const float*)d_in[8];
    float* out = (float*)d_out;

    char* ws = (char*)d_ws;
    const size_t MB = 1u << 20;
    unsigned short* xb  = (unsigned short*)(ws + 0 * MB);   // 8 MB [4096,1024]
    unsigned short* wqb = (unsigned short*)(ws + 8 * MB);   // 2 MB
    unsigned short* wkb = (unsigned short*)(ws + 10 * MB);  // 2 MB
    unsigned short* wvb = (unsigned short*)(ws + 12 * MB);  // 2 MB
    unsigned short* wob = (unsigned short*)(ws + 14 * MB);  // 2 MB
    unsigned short* qw  = (unsigned short*)(ws + 16 * MB);  // 8 MB [B,H,T,64]
    unsigned short* kw  = (unsigned short*)(ws + 24 * MB);  // 8 MB [B,H,T,64]
    unsigned short* vtw = (unsigned short*)(ws + 32 * MB);  // 8 MB [B,H,64,T]
    unsigned short* ow  = (unsigned short*)(ws + 40 * MB);  // 8 MB [B*T,1024]

    cvt5<<<dim3(1024, 1, 5), dim3(256), 0, stream>>>(
        x, Wq, Wk, Wv, Wo, xb, wqb, wkb, wvb, wob,
        B_NUM * T_LEN * D_DIM, D_DIM * D_DIM, D_DIM * D_DIM, D_DIM * D_DIM, D_DIM * D_DIM);

    gemm_qkv<<<dim3((B_NUM * T_LEN) / 128, D_DIM / 128, 3), dim3(256), 0, stream>>>(
        xb, wqb, wkb, wvb, bq, bk, bv, qw, kw, vtw);

    attn<<<dim3(512), dim3(256), 0, stream>>>(qw, kw, vtw, ow);

    gemm_out<<<dim3((B_NUM * T_LEN) / 128, D_DIM / 128), dim3(256), 0, stream>>>(
        ow, wob, bo, out);
}